// Round 4
// baseline (94.038 us; speedup 1.0000x reference)
//
#include <hip/hip_runtime.h>

// Problem constants (reference: B,N,D,OUT = 4,512,128,128)
#define B_ 4
#define N_ 512
#define D_ 128
#define O_ 128
#define OS 16     // o-slice width per block
#define IT 64     // i-rows per block

// ---------------------------------------------------------------------------
// Single fused kernel, no workspace, no cooperative sync.
// Block = (b, i-tile of 64 rows, o-slice of 16 cols); grid = 4*8*8 = 256.
//
// Phase A: q-slice = x[b] @ W2[:, os]  (ALL 512 rows, this block's 16 o's)
//          -> LDS transposed qsT[16][512+4]. 8x redundant across i-tiles,
//          but only 268M FMA chip-wide (3.4 us at 157 TF) -- far cheaper
//          than the 2 MB global round-trip + L3 re-reads + second dispatch
//          it replaces (R0-R3 evidence: two-kernel skeleton pinned at
//          ~30 us regardless of TLP/ILP tuning).
//          The 2 waves whose rows coincide with the i-tile also compute
//          phat = x @ (W1-W2) for their 64 rows (wave-uniform branch).
//
// Phase B: out[b,i,o] = relu(phat + max_j fma(adj[b,i,j],1024,qsT[o][j]) - 1024)
//          Mask trick as before (adj in {0,1}, |q|,|phat| << 1024; empty
//          rows go negative -> relu -> 0, matching reference).
//          Thread = (wave i-quad, oo, js): per iteration the 4 adj-row
//          loads of a wave cover ONE contiguous 64B line (js*16B offsets),
//          and qsT rows are padded to 516 so oo spreads across banks.
// ---------------------------------------------------------------------------
__global__ __launch_bounds__(1024, 4)
void edgeconv_fused(const float* __restrict__ x, const float* __restrict__ adj,
                    const float* __restrict__ W, const float* __restrict__ bias,
                    float* __restrict__ out) {
    __shared__ float W2s[D_][OS];          // 8 KB   W2 slice [k][o]
    __shared__ float Wds[D_][OS];          // 8 KB   (W1-W2) slice
    __shared__ float qsT[OS][N_ + 4];      // 33 KB  q-slice, transposed [o][j]
    __shared__ float phs[IT][OS];          // 4 KB   phat for the i-tile
    __shared__ float part[IT][OS][5];      // 20 KB  phase-B partials (js-split)

    const int tid   = threadIdx.x;
    const int bid   = blockIdx.x;
    const int os    = bid & 7;
    const int it    = (bid >> 3) & 7;
    const int b     = bid >> 6;
    const int obase = os * OS;
    const int i0    = it * IT;

    // ---- stage W slices: thread -> (k, o-pair) ----
    {
        const int k  = tid >> 3;                         // 0..127
        const int oc = (tid & 7) * 2;                    // 0..14
        const float2 w1 = *(const float2*)&W[(size_t)k * O_ + obase + oc];
        const float2 w2 = *(const float2*)&W[(size_t)(k + D_) * O_ + obase + oc];
        *(float2*)&W2s[k][oc] = w2;
        *(float2*)&Wds[k][oc] = make_float2(w1.x - w2.x, w1.y - w2.y);
    }
    __syncthreads();

    // ---- Phase A: thread = (j-pair, o-quad) ----
    const int jb  = (tid >> 2) * 2;                      // 0..510
    const int oq4 = (tid & 3) * 4;                       // 0,4,8,12
    const float* __restrict__ X0 = x + ((size_t)b * N_ + jb) * D_;
    const float* __restrict__ X1 = X0 + D_;

    float aq[2][4] = {{0,0,0,0},{0,0,0,0}};
    float ap[2][4] = {{0,0,0,0},{0,0,0,0}};
    const bool in_tile = (jb >= i0) && (jb < i0 + IT);   // wave-uniform

    if (in_tile) {
#pragma unroll 4
        for (int kc = 0; kc < 16; ++kc) {                // 8 k's per chunk
            float xr0[8], xr1[8];
            *(float4*)&xr0[0] = *(const float4*)&X0[kc * 8];
            *(float4*)&xr0[4] = *(const float4*)&X0[kc * 8 + 4];
            *(float4*)&xr1[0] = *(const float4*)&X1[kc * 8];
            *(float4*)&xr1[4] = *(const float4*)&X1[kc * 8 + 4];
#pragma unroll
            for (int kk = 0; kk < 8; ++kk) {
                const float4 wq = *(const float4*)&W2s[kc * 8 + kk][oq4];
                const float4 wd = *(const float4*)&Wds[kc * 8 + kk][oq4];
                const float x0 = xr0[kk], x1 = xr1[kk];
                aq[0][0] = fmaf(x0, wq.x, aq[0][0]);
                aq[0][1] = fmaf(x0, wq.y, aq[0][1]);
                aq[0][2] = fmaf(x0, wq.z, aq[0][2]);
                aq[0][3] = fmaf(x0, wq.w, aq[0][3]);
                aq[1][0] = fmaf(x1, wq.x, aq[1][0]);
                aq[1][1] = fmaf(x1, wq.y, aq[1][1]);
                aq[1][2] = fmaf(x1, wq.z, aq[1][2]);
                aq[1][3] = fmaf(x1, wq.w, aq[1][3]);
                ap[0][0] = fmaf(x0, wd.x, ap[0][0]);
                ap[0][1] = fmaf(x0, wd.y, ap[0][1]);
                ap[0][2] = fmaf(x0, wd.z, ap[0][2]);
                ap[0][3] = fmaf(x0, wd.w, ap[0][3]);
                ap[1][0] = fmaf(x1, wd.x, ap[1][0]);
                ap[1][1] = fmaf(x1, wd.y, ap[1][1]);
                ap[1][2] = fmaf(x1, wd.z, ap[1][2]);
                ap[1][3] = fmaf(x1, wd.w, ap[1][3]);
            }
        }
    } else {
#pragma unroll 4
        for (int kc = 0; kc < 16; ++kc) {
            float xr0[8], xr1[8];
            *(float4*)&xr0[0] = *(const float4*)&X0[kc * 8];
            *(float4*)&xr0[4] = *(const float4*)&X0[kc * 8 + 4];
            *(float4*)&xr1[0] = *(const float4*)&X1[kc * 8];
            *(float4*)&xr1[4] = *(const float4*)&X1[kc * 8 + 4];
#pragma unroll
            for (int kk = 0; kk < 8; ++kk) {
                const float4 wq = *(const float4*)&W2s[kc * 8 + kk][oq4];
                const float x0 = xr0[kk], x1 = xr1[kk];
                aq[0][0] = fmaf(x0, wq.x, aq[0][0]);
                aq[0][1] = fmaf(x0, wq.y, aq[0][1]);
                aq[0][2] = fmaf(x0, wq.z, aq[0][2]);
                aq[0][3] = fmaf(x0, wq.w, aq[0][3]);
                aq[1][0] = fmaf(x1, wq.x, aq[1][0]);
                aq[1][1] = fmaf(x1, wq.y, aq[1][1]);
                aq[1][2] = fmaf(x1, wq.z, aq[1][2]);
                aq[1][3] = fmaf(x1, wq.w, aq[1][3]);
            }
        }
    }

    // q-slice -> LDS transposed ([o][j]; j-pair contiguous -> float2)
#pragma unroll
    for (int c = 0; c < 4; ++c)
        *(float2*)&qsT[oq4 + c][jb] = make_float2(aq[0][c], aq[1][c]);

    if (in_tile) {
        const int il = jb - i0;
#pragma unroll
        for (int c = 0; c < 4; ++c) {
            phs[il][oq4 + c]     = ap[0][c];
            phs[il + 1][oq4 + c] = ap[1][c];
        }
    }
    __syncthreads();

    // ---- Phase B: thread = (wave -> 4 i-rows, oo, js) ----
    {
        const int oo = tid & 15;
        const int js = (tid >> 4) & 3;
        const int ib = (tid >> 6) * 4;                   // wave-uniform i-quad
        const float* __restrict__ arow = adj + ((size_t)b * N_ + i0 + ib) * N_;

        float m0 = -1e30f, m1 = -1e30f, m2 = -1e30f, m3 = -1e30f;
#pragma unroll 2
        for (int t = 0; t < 32; ++t) {
            const int j4 = js * 4 + t * 16;              // js-interleaved chunks
            const float4 qv = *(const float4*)&qsT[oo][j4];
            const float4 a0 = *(const float4*)&arow[0 * N_ + j4];
            const float4 a1 = *(const float4*)&arow[1 * N_ + j4];
            const float4 a2 = *(const float4*)&arow[2 * N_ + j4];
            const float4 a3 = *(const float4*)&arow[3 * N_ + j4];
            m0 = fmaxf(m0, fmaxf(fmaxf(fmaf(a0.x, 1024.0f, qv.x), fmaf(a0.y, 1024.0f, qv.y)),
                                 fmaxf(fmaf(a0.z, 1024.0f, qv.z), fmaf(a0.w, 1024.0f, qv.w))));
            m1 = fmaxf(m1, fmaxf(fmaxf(fmaf(a1.x, 1024.0f, qv.x), fmaf(a1.y, 1024.0f, qv.y)),
                                 fmaxf(fmaf(a1.z, 1024.0f, qv.z), fmaf(a1.w, 1024.0f, qv.w))));
            m2 = fmaxf(m2, fmaxf(fmaxf(fmaf(a2.x, 1024.0f, qv.x), fmaf(a2.y, 1024.0f, qv.y)),
                                 fmaxf(fmaf(a2.z, 1024.0f, qv.z), fmaf(a2.w, 1024.0f, qv.w))));
            m3 = fmaxf(m3, fmaxf(fmaxf(fmaf(a3.x, 1024.0f, qv.x), fmaf(a3.y, 1024.0f, qv.y)),
                                 fmaxf(fmaf(a3.z, 1024.0f, qv.z), fmaf(a3.w, 1024.0f, qv.w))));
        }
        part[ib + 0][oo][js] = m0;
        part[ib + 1][oo][js] = m1;
        part[ib + 2][oo][js] = m2;
        part[ib + 3][oo][js] = m3;
    }
    __syncthreads();

    // ---- epilogue: 1 output per thread ----
    {
        const int il = tid >> 4;                         // 0..63
        const int oo = tid & 15;
        const float mm = fmaxf(fmaxf(part[il][oo][0], part[il][oo][1]),
                               fmaxf(part[il][oo][2], part[il][oo][3]));
        const float v = phs[il][oo] + bias[obase + oo] + mm - 1024.0f;
        out[((size_t)b * N_ + i0 + il) * O_ + obase + oo] = fmaxf(v, 0.0f);
    }
}

// ---------------------------------------------------------------------------
extern "C" void kernel_launch(void* const* d_in, const int* in_sizes, int n_in,
                              void* d_out, int out_size, void* d_ws, size_t ws_size,
                              hipStream_t stream) {
    const float* x    = (const float*)d_in[0];   // (B,N,D)
    const float* adj  = (const float*)d_in[1];   // (B,N,N)
    const float* W    = (const float*)d_in[2];   // (2D, OUT)
    const float* bias = (const float*)d_in[3];   // (OUT,)
    float* out = (float*)d_out;                  // (B,N,OUT)

    (void)d_ws; (void)ws_size;                   // no workspace: q lives in LDS

    edgeconv_fused<<<B_ * 8 * 8, 1024, 0, stream>>>(x, adj, W, bias, out);
}